// Round 4
// baseline (46.618 us; speedup 1.0000x reference)
//
#include <hip/hip_runtime.h>

// TopKRouter: x (4,8192,1024) f32, W (8,1024) f32
// out = [router_output (4,8192,8) f32 | top_idx (4,8192,2) written as f32 values]
//
// Round-1 structure (known-good, passed post-timing) with the within-row
// butterfly steps (s=1,2,4,8) moved from __shfl_xor (LDS pipe) to the
// standard rocPRIM DPP reduction modes (VALU pipe), full row/bank masks:
//   s=1 -> quad_perm(1,0,3,2)   s=2 -> quad_perm(2,3,0,1)
//   s=4 -> row_half_mirror      s=8 -> row_mirror
// (bit-identical pairings: quad/8-block sums are replicated before mirrors)
// Cross-row steps s=16,32 remain __shfl_xor exactly as in round 1, so the
// full summation tree is bit-identical to the passing kernel.

constexpr int Cc = 1024;
constexpr int Ec = 8;
constexpr int TOKENS = 4 * 8192;          // 32768
constexpr int TPW = 4;                    // tokens per wave
constexpr int WPB = 4;                    // waves per block
constexpr int BLOCK = WPB * 64;           // 256
constexpr int TPB = TPW * WPB;            // 16 tokens per block
constexpr int GRID = TOKENS / TPB;        // 2048

template<int CTRL>
__device__ __forceinline__ float dpp_full(float v) {
    // full row_mask/bank_mask, bound_ctrl=false: every lane written from an
    // in-row valid source; 'old' (0) is never observable.
    int r = __builtin_amdgcn_update_dpp(0, __float_as_int(v), CTRL, 0xF, 0xF, false);
    return __int_as_float(r);
}

__global__ __launch_bounds__(BLOCK) void topk_router_kernel(
    const float* __restrict__ x, const float* __restrict__ W, float* __restrict__ out)
{
    __shared__ float Ws[Ec * Cc];         // 32 KB
    const int tid = threadIdx.x;

    // Cooperative W stage: 2048 float4 over 256 threads = 8 each
    {
        const float4* Wg4 = reinterpret_cast<const float4*>(W);
        float4* Ws4 = reinterpret_cast<float4*>(Ws);
        #pragma unroll
        for (int i = 0; i < (Ec * Cc / 4) / BLOCK; ++i)
            Ws4[tid + i * BLOCK] = Wg4[tid + i * BLOCK];
    }
    __syncthreads();

    const int lane = tid & 63;
    const int wave = tid >> 6;
    const int t0 = (blockIdx.x * WPB + wave) * TPW;

    float acc[TPW][Ec];
    #pragma unroll
    for (int t = 0; t < TPW; ++t)
        #pragma unroll
        for (int e = 0; e < Ec; ++e) acc[t][e] = 0.f;

    const float* xp = x + (size_t)t0 * Cc;

    // Identical per-lane partial accumulation to round 1:
    // lane covers columns {it*256 + lane*4 .. +3}, it = 0..3.
    #pragma unroll
    for (int it = 0; it < Cc / 256; ++it) {
        const int cb = it * 256 + lane * 4;
        float4 xv[TPW];
        #pragma unroll
        for (int t = 0; t < TPW; ++t)
            xv[t] = *reinterpret_cast<const float4*>(xp + (size_t)t * Cc + cb);
        #pragma unroll
        for (int e = 0; e < Ec; ++e) {
            float4 wv = *reinterpret_cast<const float4*>(&Ws[e * Cc + cb]);
            #pragma unroll
            for (int t = 0; t < TPW; ++t) {
                acc[t][e] += xv[t].x * wv.x;
                acc[t][e] += xv[t].y * wv.y;
                acc[t][e] += xv[t].z * wv.z;
                acc[t][e] += xv[t].w * wv.w;
            }
        }
    }

    // Within-row butterfly via standard DPP modes (VALU pipe), bit-identical
    // to shfl_xor s=1,2,4,8.
#define DSTEP(CTRL)                                     \
    _Pragma("unroll")                                   \
    for (int t = 0; t < TPW; ++t) {                     \
        _Pragma("unroll")                               \
        for (int e = 0; e < Ec; ++e)                    \
            acc[t][e] += dpp_full<(CTRL)>(acc[t][e]);   \
    }
    DSTEP(0xB1)    // quad_perm(1,0,3,2)  == xor 1
    DSTEP(0x4E)    // quad_perm(2,3,0,1)  == xor 2
    DSTEP(0x141)   // row_half_mirror     == xor 4 (quad sums replicated)
    DSTEP(0x140)   // row_mirror          == xor 8 (8-block sums replicated)
#undef DSTEP

    // Cross-row steps exactly as round 1 (LDS pipe, 64 wave-instrs total)
    #pragma unroll
    for (int s = 16; s < 64; s <<= 1)
        #pragma unroll
        for (int t = 0; t < TPW; ++t)
            #pragma unroll
            for (int e = 0; e < Ec; ++e)
                acc[t][e] += __shfl_xor(acc[t][e], s, 64);

    // Epilogue: all lanes now hold identical full sums (as in round 1).
    // Lane tsel (= lane & 3) handles token t0 + tsel; lanes 0..3 store.
    const int tsel = lane & 3;
    float pe[Ec];
    #pragma unroll
    for (int e = 0; e < Ec; ++e) {
        float v = acc[0][e];
        v = (tsel == 1) ? acc[1][e] : v;
        v = (tsel == 2) ? acc[2][e] : v;
        v = (tsel == 3) ? acc[3][e] : v;
        pe[e] = v;
    }

    float m = pe[0];
    #pragma unroll
    for (int e = 1; e < Ec; ++e) m = fmaxf(m, pe[e]);
    float ssum = 0.f;
    #pragma unroll
    for (int e = 0; e < Ec; ++e) { pe[e] = __expf(pe[e] - m); ssum += pe[e]; }
    const float inv = 1.0f / ssum;
    #pragma unroll
    for (int e = 0; e < Ec; ++e) pe[e] *= inv;

    // top-1 then top-2 (strict >, ascending scan -> lowest index on ties,
    // matching jax.lax.top_k)
    int i1 = 0; float v1 = pe[0];
    #pragma unroll
    for (int e = 1; e < Ec; ++e) { if (pe[e] > v1) { v1 = pe[e]; i1 = e; } }
    int i2 = -1; float v2 = -1.f;
    #pragma unroll
    for (int e = 0; e < Ec; ++e) { if (e != i1 && pe[e] > v2) { v2 = pe[e]; i2 = e; } }

    if (lane < TPW) {
        const int tok = t0 + tsel;
        float r[8];
        #pragma unroll
        for (int e = 0; e < Ec; ++e)
            r[e] = (e == i1) ? v1 : ((e == i2) ? v2 : 0.f);
        float4* o4 = reinterpret_cast<float4*>(out + (size_t)tok * Ec);
        o4[0] = make_float4(r[0], r[1], r[2], r[3]);
        o4[1] = make_float4(r[4], r[5], r[6], r[7]);
        float2* oi = reinterpret_cast<float2*>(out + (size_t)TOKENS * Ec + (size_t)tok * 2);
        *oi = make_float2((float)i1, (float)i2);
    }
}

extern "C" void kernel_launch(void* const* d_in, const int* in_sizes, int n_in,
                              void* d_out, int out_size, void* d_ws, size_t ws_size,
                              hipStream_t stream) {
    const float* x = (const float*)d_in[0];
    const float* W = (const float*)d_in[1];
    float* out = (float*)d_out;
    hipLaunchKernelGGL(topk_router_kernel, dim3(GRID), dim3(BLOCK), 0, stream,
                       x, W, out);
}

// Round 5
// 43.958 us; speedup vs baseline: 1.0605x; 1.0605x over previous
//
#include <hip/hip_runtime.h>

// TopKRouter: x (4,8192,1024) f32, W (8,1024) f32
// out = [router_output (4,8192,8) f32 | top_idx (4,8192,2) written as f32 values]
//
// Round-4 math (passed, deterministic) with two changes:
//  1. x loads are NON-TEMPORAL (stream-once data): avoids allocating 128 MB
//     in L2/LLC, so the timed window doesn't pay dirty-poison writebacks,
//     and warm replay == cold == HBM-bound (no warm-cache artifact).
//  2. All 16 x loads are issued BEFORE the W LDS stage + barrier, so the
//     stage latency hides under the x HBM latency on a cold run.
// Summation order is bit-identical to round 4 (DPP quad_perm/mirrors for
// s=1..8, __shfl_xor for s=16,32).

typedef float f32x4 __attribute__((ext_vector_type(4)));

constexpr int Cc = 1024;
constexpr int Ec = 8;
constexpr int TOKENS = 4 * 8192;          // 32768
constexpr int TPW = 4;                    // tokens per wave
constexpr int WPB = 4;                    // waves per block
constexpr int BLOCK = WPB * 64;           // 256
constexpr int TPB = TPW * WPB;            // 16 tokens per block
constexpr int GRID = TOKENS / TPB;        // 2048

template<int CTRL>
__device__ __forceinline__ float dpp_full(float v) {
    int r = __builtin_amdgcn_update_dpp(0, __float_as_int(v), CTRL, 0xF, 0xF, false);
    return __int_as_float(r);
}

__global__ __launch_bounds__(BLOCK) void topk_router_kernel(
    const float* __restrict__ x, const float* __restrict__ W, float* __restrict__ out)
{
    __shared__ float Ws[Ec * Cc];         // 32 KB
    const int tid = threadIdx.x;
    const int lane = tid & 63;
    const int wave = tid >> 6;
    const int t0 = (blockIdx.x * WPB + wave) * TPW;
    const float* xp = x + (size_t)t0 * Cc;

    // ---- issue ALL x loads first (non-temporal, 16 outstanding) ----
    f32x4 xv[4][TPW];
    #pragma unroll
    for (int it = 0; it < Cc / 256; ++it) {
        const int cb = it * 256 + lane * 4;
        #pragma unroll
        for (int t = 0; t < TPW; ++t)
            xv[it][t] = __builtin_nontemporal_load(
                reinterpret_cast<const f32x4*>(xp + (size_t)t * Cc + cb));
    }

    // ---- W stage overlaps with x loads in flight ----
    {
        const f32x4* Wg4 = reinterpret_cast<const f32x4*>(W);
        f32x4* Ws4 = reinterpret_cast<f32x4*>(Ws);
        #pragma unroll
        for (int i = 0; i < (Ec * Cc / 4) / BLOCK; ++i)
            Ws4[tid + i * BLOCK] = Wg4[tid + i * BLOCK];
    }
    __syncthreads();

    float acc[TPW][Ec];
    #pragma unroll
    for (int t = 0; t < TPW; ++t)
        #pragma unroll
        for (int e = 0; e < Ec; ++e) acc[t][e] = 0.f;

    // Identical accumulation order to rounds 1/4: it-major, then e, then t,
    // components x,y,z,w in order.
    #pragma unroll
    for (int it = 0; it < Cc / 256; ++it) {
        const int cb = it * 256 + lane * 4;
        #pragma unroll
        for (int e = 0; e < Ec; ++e) {
            f32x4 wv = *reinterpret_cast<const f32x4*>(&Ws[e * Cc + cb]);
            #pragma unroll
            for (int t = 0; t < TPW; ++t) {
                acc[t][e] += xv[it][t].x * wv.x;
                acc[t][e] += xv[it][t].y * wv.y;
                acc[t][e] += xv[it][t].z * wv.z;
                acc[t][e] += xv[it][t].w * wv.w;
            }
        }
    }

    // Within-row butterfly via standard DPP modes (bit-identical to xor 1,2,4,8)
#define DSTEP(CTRL)                                     \
    _Pragma("unroll")                                   \
    for (int t = 0; t < TPW; ++t) {                     \
        _Pragma("unroll")                               \
        for (int e = 0; e < Ec; ++e)                    \
            acc[t][e] += dpp_full<(CTRL)>(acc[t][e]);   \
    }
    DSTEP(0xB1)    // quad_perm(1,0,3,2)  == xor 1
    DSTEP(0x4E)    // quad_perm(2,3,0,1)  == xor 2
    DSTEP(0x141)   // row_half_mirror     == xor 4
    DSTEP(0x140)   // row_mirror          == xor 8
#undef DSTEP

    // Cross-row steps exactly as round 1 (LDS pipe)
    #pragma unroll
    for (int s = 16; s < 64; s <<= 1)
        #pragma unroll
        for (int t = 0; t < TPW; ++t)
            #pragma unroll
            for (int e = 0; e < Ec; ++e)
                acc[t][e] += __shfl_xor(acc[t][e], s, 64);

    // Epilogue: all lanes hold identical full sums.
    const int tsel = lane & 3;
    float pe[Ec];
    #pragma unroll
    for (int e = 0; e < Ec; ++e) {
        float v = acc[0][e];
        v = (tsel == 1) ? acc[1][e] : v;
        v = (tsel == 2) ? acc[2][e] : v;
        v = (tsel == 3) ? acc[3][e] : v;
        pe[e] = v;
    }

    float m = pe[0];
    #pragma unroll
    for (int e = 1; e < Ec; ++e) m = fmaxf(m, pe[e]);
    float ssum = 0.f;
    #pragma unroll
    for (int e = 0; e < Ec; ++e) { pe[e] = __expf(pe[e] - m); ssum += pe[e]; }
    const float inv = 1.0f / ssum;
    #pragma unroll
    for (int e = 0; e < Ec; ++e) pe[e] *= inv;

    // top-1 then top-2 (strict >, ascending scan -> lowest index on ties)
    int i1 = 0; float v1 = pe[0];
    #pragma unroll
    for (int e = 1; e < Ec; ++e) { if (pe[e] > v1) { v1 = pe[e]; i1 = e; } }
    int i2 = -1; float v2 = -1.f;
    #pragma unroll
    for (int e = 0; e < Ec; ++e) { if (e != i1 && pe[e] > v2) { v2 = pe[e]; i2 = e; } }

    if (lane < TPW) {
        const int tok = t0 + tsel;
        float r[8];
        #pragma unroll
        for (int e = 0; e < Ec; ++e)
            r[e] = (e == i1) ? v1 : ((e == i2) ? v2 : 0.f);
        float4* o4 = reinterpret_cast<float4*>(out + (size_t)tok * Ec);
        o4[0] = make_float4(r[0], r[1], r[2], r[3]);
        o4[1] = make_float4(r[4], r[5], r[6], r[7]);
        float2* oi = reinterpret_cast<float2*>(out + (size_t)TOKENS * Ec + (size_t)tok * 2);
        *oi = make_float2((float)i1, (float)i2);
    }
}

extern "C" void kernel_launch(void* const* d_in, const int* in_sizes, int n_in,
                              void* d_out, int out_size, void* d_ws, size_t ws_size,
                              hipStream_t stream) {
    const float* x = (const float*)d_in[0];
    const float* W = (const float*)d_in[1];
    float* out = (float*)d_out;
    hipLaunchKernelGGL(topk_router_kernel, dim3(GRID), dim3(BLOCK), 0, stream,
                       x, W, out);
}